// Round 1
// baseline (455.396 us; speedup 1.0000x reference)
//
#include <hip/hip_runtime.h>
#include <hip/hip_bf16.h>

// TreeMLP fused kernel for MI355X (gfx950).
//
// Math: for level l: out_l = gelu( (x with first l*128 feats zeroed) @ W1 + b1 ) @ W2 + b2
// Key identity: pre_l = b1 + sum_{j>=l} x_blockj @ W1_blockj  -> reverse-order K-loop
// with accumulator snapshots; GEMM2 fused per snapshot (h never materialized).
//
// ws layout (fp16 elems):
//   xt : [256 tile16][32 kt][64 lane][8]  = 4,194,304   (A-fragment lane order)
//   w1t: [32 kt][256 nt][64 lane][8]      = 4,194,304   (B-fragment lane order)
//   w2t: [128 kt2][8 ntr][64 lane][8]     =   524,288   (B-fragment lane order)
// total ws = 17,825,792 bytes.

typedef _Float16 half8 __attribute__((ext_vector_type(8)));
typedef float    f32x4 __attribute__((ext_vector_type(4)));

#define EDIM 1024
#define HDIM 4096
#define RDIM 128

__device__ __forceinline__ float gelu_f(float x){
  // 0.5x(1+tanh(c(x+0.044715x^3))) == x * sigmoid(x*(2c + 2c*0.044715*x^2))
  float t2 = x * fmaf(x*x, 0.07135481283840494f, 1.5957691216057308f);
  float e  = __expf(-t2);
  return x * __builtin_amdgcn_rcpf(1.0f + e);
}

// ---- prep: cast fp32 -> fp16 and tile into MFMA fragment lane order ----

__global__ void k_prep_x(const float* __restrict__ x, _Float16* __restrict__ xt){
  int tid  = blockIdx.x*256 + threadIdx.x;      // 524288 frags of 8
  int lane = tid & 63;
  int kt   = (tid >> 6) & 31;
  int t16  = tid >> 11;
  int m = lane & 15, kq = lane >> 4;
  const float4* s4 = reinterpret_cast<const float4*>(x + (t16*16 + m)*EDIM + kt*32 + kq*8);
  float4 a = s4[0], b = s4[1];
  half8 v;
  v[0]=(_Float16)a.x; v[1]=(_Float16)a.y; v[2]=(_Float16)a.z; v[3]=(_Float16)a.w;
  v[4]=(_Float16)b.x; v[5]=(_Float16)b.y; v[6]=(_Float16)b.z; v[7]=(_Float16)b.w;
  *reinterpret_cast<half8*>(xt + (size_t)tid*8) = v;
}

__global__ void k_prep_w1(const float* __restrict__ w1, _Float16* __restrict__ w1t){
  int tid  = blockIdx.x*256 + threadIdx.x;      // 524288 frags
  int lane = tid & 63;
  int tile = tid >> 6;
  int nt = tile & 255, kt = tile >> 8;
  int n = nt*16 + (lane & 15);
  int k = kt*32 + (lane >> 4)*8;
  const float* src = w1 + (size_t)k*HDIM + n;
  half8 v;
  #pragma unroll
  for (int jj = 0; jj < 8; ++jj) v[jj] = (_Float16)src[(size_t)jj*HDIM];
  *reinterpret_cast<half8*>(w1t + (size_t)tid*8) = v;
}

__global__ void k_prep_w2(const float* __restrict__ w2, _Float16* __restrict__ w2t){
  int tid  = blockIdx.x*256 + threadIdx.x;      // 65536 frags
  int lane = tid & 63;
  int tile = tid >> 6;
  int ntr = tile & 7, kt2 = tile >> 3;
  int n = ntr*16 + (lane & 15);
  int k = kt2*32 + (lane >> 4)*8;
  const float* src = w2 + (size_t)k*RDIM + n;
  half8 v;
  #pragma unroll
  for (int jj = 0; jj < 8; ++jj) v[jj] = (_Float16)src[(size_t)jj*RDIM];
  *reinterpret_cast<half8*>(w2t + (size_t)tid*8) = v;
}

__global__ void k_init_out(const float* __restrict__ b2, float* __restrict__ out){
  int i = blockIdx.x*256 + threadIdx.x;         // 1048576 float4s
  float4 bv = reinterpret_cast<const float4*>(b2)[i & 31];
  reinterpret_cast<float4*>(out)[i] = bv;
}

// ---- main fused kernel ----
// grid 256 blocks x 512 threads (8 waves).
// block -> (token-tile of 32, H-half of 2048); XCD-grouped so each XCD's L2
// holds one 4MB W1-half.  wave (mg, wr): mg = token subgroup of 16, wr = 32-col slice.
// Per h-tile of 128: GEMM1 (K reversed j=7..0, snapshot+gelu per j) -> LDS ->
// GEMM2 accumulate out[j] in regs.  Partial halves combined via atomicAdd.

__global__ __launch_bounds__(512, 2) void k_treemlp(
    const _Float16* __restrict__ xt, const _Float16* __restrict__ w1t,
    const _Float16* __restrict__ w2t, const float* __restrict__ b1,
    float* __restrict__ out){
  int b   = blockIdx.x;
  int g   = b & 7;                 // pseudo-XCD slot
  int hh  = g >> 2;                // H half: 0/1
  int tt  = (b >> 3)*4 + (b & 3);  // token tile 0..127 (32 tokens each)
  int w    = threadIdx.x >> 6;
  int lane = threadIdx.x & 63;
  int mg = w >> 2, wr = w & 3;
  int m16 = lane & 15, q = lane >> 4;

  __shared__ _Float16 hs[2*8*512];   // double-buffered P-matrix (A-layout tiles)

  f32x4 outA[8][2];
  #pragma unroll
  for (int j = 0; j < 8; ++j){
    outA[j][0] = f32x4{0.f,0.f,0.f,0.f};
    outA[j][1] = f32x4{0.f,0.f,0.f,0.f};
  }

  const _Float16* xbase  = xt + (size_t)(tt*2 + mg)*16384 + lane*8;   // + kt*512
  const _Float16* w2base = w2t + (size_t)(wr*2)*512 + lane*8;         // + ((kt2*8)+t)*512

  for (int ht = 0; ht < 16; ++ht){
    int ktb = hh*64 + ht*4;           // global 32-row K-tile base into W2
    half8 w2f[4][2];
    #pragma unroll
    for (int s = 0; s < 4; ++s)
      #pragma unroll
      for (int t = 0; t < 2; ++t)
        w2f[s][t] = *reinterpret_cast<const half8*>(w2base + (size_t)((ktb+s)*8 + t)*512);

    float b1v[2];
    #pragma unroll
    for (int t = 0; t < 2; ++t)
      b1v[t] = b1[hh*2048 + ht*128 + wr*32 + t*16 + m16];

    f32x4 acc1[2];
    acc1[0] = f32x4{0.f,0.f,0.f,0.f};
    acc1[1] = f32x4{0.f,0.f,0.f,0.f};

    #pragma unroll
    for (int jr = 0; jr < 8; ++jr){
      int j = 7 - jr;                  // reverse K-block order -> suffix sums
      // GEMM1: acc1 += x_blockj @ W1[j-block, htile-slice]
      #pragma unroll
      for (int s = 0; s < 4; ++s){
        int kt = j*4 + s;
        half8 af = *reinterpret_cast<const half8*>(xbase + (size_t)kt*512);
        #pragma unroll
        for (int t = 0; t < 2; ++t){
          int ntg = hh*128 + ht*8 + wr*2 + t;
          half8 bf = *reinterpret_cast<const half8*>(w1t + (size_t)(kt*256 + ntg)*512 + lane*8);
          acc1[t] = __builtin_amdgcn_mfma_f32_16x16x32_f16(af, bf, acc1[t], 0, 0, 0);
        }
      }
      // snapshot -> gelu -> LDS (C-layout -> A-layout tiles); each wave owns tile mg*4+wr
      _Float16* hbuf = hs + (jr & 1)*4096 + (mg*4 + wr)*512;
      #pragma unroll
      for (int t = 0; t < 2; ++t){
        int cc = t*16 + m16;           // col within wave's 32-col slice
        #pragma unroll
        for (int i = 0; i < 4; ++i){
          float v = gelu_f(acc1[t][i] + b1v[t]);
          hbuf[((cc >> 3)*16 + q*4 + i)*8 + (cc & 7)] = (_Float16)v;
        }
      }
      __syncthreads();                 // single barrier per level (double-buffered hs)
      // GEMM2: out[j] += h_j @ W2[htile-slice, wave's 32 r-cols]
      const _Float16* rbuf = hs + (jr & 1)*4096 + mg*2048 + lane*8;
      #pragma unroll
      for (int s = 0; s < 4; ++s){
        half8 a2 = *reinterpret_cast<const half8*>(rbuf + s*512);
        #pragma unroll
        for (int t = 0; t < 2; ++t)
          outA[j][t] = __builtin_amdgcn_mfma_f32_16x16x32_f16(a2, w2f[s][t], outA[j][t], 0, 0, 0);
      }
    }
  }

  // combine H-halves: atomicAdd onto b2-initialized d_out
  float* ob = out + (size_t)(tt*32 + mg*16 + q*4)*1024 + wr*32 + m16;
  #pragma unroll
  for (int j = 0; j < 8; ++j)
    #pragma unroll
    for (int t = 0; t < 2; ++t)
      #pragma unroll
      for (int i = 0; i < 4; ++i)
        atomicAdd(&ob[i*1024 + j*128 + t*16], outA[j][t][i]);
}

extern "C" void kernel_launch(void* const* d_in, const int* in_sizes, int n_in,
                              void* d_out, int out_size, void* d_ws, size_t ws_size,
                              hipStream_t stream){
  (void)in_sizes; (void)n_in; (void)out_size; (void)ws_size;
  const float* x  = (const float*)d_in[0];
  const float* W1 = (const float*)d_in[1];
  const float* b1 = (const float*)d_in[2];
  const float* W2 = (const float*)d_in[3];
  const float* b2 = (const float*)d_in[4];
  float* out = (float*)d_out;

  _Float16* xt  = (_Float16*)d_ws;
  _Float16* w1t = xt  + 4194304;
  _Float16* w2t = w1t + 4194304;

  hipLaunchKernelGGL(k_prep_x,  dim3(2048), dim3(256), 0, stream, x,  xt);
  hipLaunchKernelGGL(k_prep_w1, dim3(2048), dim3(256), 0, stream, W1, w1t);
  hipLaunchKernelGGL(k_prep_w2, dim3(256),  dim3(256), 0, stream, W2, w2t);
  hipLaunchKernelGGL(k_init_out, dim3(4096), dim3(256), 0, stream, b2, out);
  hipLaunchKernelGGL(k_treemlp, dim3(256), dim3(512), 0, stream, xt, w1t, w2t, b1, out);
}

// Round 2
// 399.441 us; speedup vs baseline: 1.1401x; 1.1401x over previous
//
#include <hip/hip_runtime.h>
#include <hip/hip_bf16.h>

// TreeMLP fused kernel for MI355X (gfx950), round 2.
//
// pre_l = b1 + sum_{j>=l} x_blockj @ W1_blockj  -> reverse-order K-loop with
// snapshots; GEMM2 fused per snapshot. R2 changes vs R1:
//  - wave tile 32tok x 32hcol (2A x 2B frags -> 4 MFMA/kt, register reuse)
//  - H-split 4, grid 512, XCD-grouped: per-XCD W1 slice 2MB (L2-resident)
//  - W2 fragments hoisted to registers per h-tile (jr-invariant)
//  - XOR-swizzled P LDS layout (8-way -> 4-way write conflicts)
//  - all prep fused into one kernel (launch-gap reduction)
//
// ws layout (fp16 elems):
//   xt : [256 t16][32 kt][64 lane][8]  (A-frag order)
//   w1t: [32 kt][256 nt][64 lane][8]   (B-frag order)
//   w2t: [128 kt2][8 ntr][64 lane][8]  (B-frag order)

typedef _Float16 half8 __attribute__((ext_vector_type(8)));
typedef float    f32x4 __attribute__((ext_vector_type(4)));

#define EDIM 1024
#define HDIM 4096
#define RDIM 128

__device__ __forceinline__ float gelu_f(float x){
  // 0.5x(1+tanh(c(x+0.044715x^3))) == x * sigmoid(x*(2c + 2c*0.044715*x^2))
  float t2 = x * fmaf(x*x, 0.07135481283840494f, 1.5957691216057308f);
  float e  = __expf(-t2);
  return x * __builtin_amdgcn_rcpf(1.0f + e);
}

// ---- fused prep: cast fp32->fp16 into MFMA fragment lane order + out init ----
__global__ void k_prep(const float* __restrict__ x, const float* __restrict__ w1,
                       const float* __restrict__ w2, const float* __restrict__ b2,
                       _Float16* __restrict__ xt, _Float16* __restrict__ w1t,
                       _Float16* __restrict__ w2t, float* __restrict__ out){
  int bid = blockIdx.x;
  if (bid < 2048){                                   // xt
    int tid = bid*256 + threadIdx.x;
    int lane = tid & 63;
    int kt   = (tid >> 6) & 31;
    int t16  = tid >> 11;
    int m = lane & 15, kq = lane >> 4;
    const float4* s4 = reinterpret_cast<const float4*>(x + (size_t)(t16*16 + m)*EDIM + kt*32 + kq*8);
    float4 a = s4[0], b = s4[1];
    half8 v;
    v[0]=(_Float16)a.x; v[1]=(_Float16)a.y; v[2]=(_Float16)a.z; v[3]=(_Float16)a.w;
    v[4]=(_Float16)b.x; v[5]=(_Float16)b.y; v[6]=(_Float16)b.z; v[7]=(_Float16)b.w;
    *reinterpret_cast<half8*>(xt + (size_t)tid*8) = v;
  } else if (bid < 4096){                            // w1t
    int tid = (bid - 2048)*256 + threadIdx.x;
    int lane = tid & 63;
    int tile = tid >> 6;
    int nt = tile & 255, kt = tile >> 8;
    int n = nt*16 + (lane & 15);
    int k = kt*32 + (lane >> 4)*8;
    const float* src = w1 + (size_t)k*HDIM + n;
    half8 v;
    #pragma unroll
    for (int jj = 0; jj < 8; ++jj) v[jj] = (_Float16)src[(size_t)jj*HDIM];
    *reinterpret_cast<half8*>(w1t + (size_t)tid*8) = v;
  } else if (bid < 4352){                            // w2t
    int tid = (bid - 4096)*256 + threadIdx.x;
    int lane = tid & 63;
    int tile = tid >> 6;
    int ntr = tile & 7, kt2 = tile >> 3;
    int n = ntr*16 + (lane & 15);
    int k = kt2*32 + (lane >> 4)*8;
    const float* src = w2 + (size_t)k*RDIM + n;
    half8 v;
    #pragma unroll
    for (int jj = 0; jj < 8; ++jj) v[jj] = (_Float16)src[(size_t)jj*RDIM];
    *reinterpret_cast<half8*>(w2t + (size_t)tid*8) = v;
  } else {                                           // out = b2 broadcast
    int i = (bid - 4352)*256 + threadIdx.x;          // 1048576 float4s
    float4 bv = reinterpret_cast<const float4*>(b2)[i & 31];
    reinterpret_cast<float4*>(out)[i] = bv;
  }
}

// ---- main fused kernel ----
// grid 512 x 512 thr (8 waves). block = (token tile of 32) x (H-quarter 1024).
// hq = (b&7)>>1 so each XCD touches ONE 2MB W1-quarter (L2-resident).
// Per h-tile of 256 cols (4 iters): W2 regs hoisted; K reversed j=7..0 with
// snapshot -> gelu -> swizzled-LDS -> GEMM2 per level.  GEMM1 wave = 32tok x
// 32col (wr 0..7); GEMM2 wave = (tg 0..1)x16tok, (rs 0..3)x32R over K=256.
__global__ __launch_bounds__(512, 2) void k_treemlp(
    const _Float16* __restrict__ xt, const _Float16* __restrict__ w1t,
    const _Float16* __restrict__ w2t, const float* __restrict__ b1,
    float* __restrict__ out){
  int b    = blockIdx.x;
  int hq   = (b & 7) >> 1;              // H-quarter, constant per XCD
  int tt   = (b >> 3)*2 + (b & 1);      // token tile 0..127
  int w    = threadIdx.x >> 6;          // wave 0..7
  int lane = threadIdx.x & 63;
  int m16 = lane & 15, q = lane >> 4;
  int m16h = m16 >> 3, m16l = m16 & 7;
  int tg = w >> 2, rs = w & 3;          // GEMM2 roles
  int lsw = lane ^ (((lane >> 4) & 3) << 1);   // swizzled LDS read lane

  __shared__ _Float16 Pbuf[2*16*64*8];  // double-buffered P, frag order, 32 KB

  f32x4 outA[8][2];
  #pragma unroll
  for (int j = 0; j < 8; ++j){
    outA[j][0] = f32x4{0.f,0.f,0.f,0.f};
    outA[j][1] = f32x4{0.f,0.f,0.f,0.f};
  }

  const _Float16* xb0 = xt + (size_t)(tt*2 + 0)*16384 + lane*8;   // + kt*512
  const _Float16* xb1 = xt + (size_t)(tt*2 + 1)*16384 + lane*8;

  for (int it = 0; it < 4; ++it){
    // hoist W2 fragments for this 256-col h-tile (jr-invariant): 16 frags
    half8 w2f[8][2];
    #pragma unroll
    for (int s = 0; s < 8; ++s)
      #pragma unroll
      for (int t = 0; t < 2; ++t)
        w2f[s][t] = *reinterpret_cast<const half8*>(
            w2t + (size_t)(((hq*32 + it*8 + s)*8) + rs*2 + t)*512 + lane*8);

    // acc1 initialized with b1 (so snapshots are pre-activation directly)
    float b1v[2];
    #pragma unroll
    for (int nf = 0; nf < 2; ++nf)
      b1v[nf] = b1[hq*1024 + it*256 + w*32 + nf*16 + m16];
    f32x4 acc1[2][2];
    #pragma unroll
    for (int tf = 0; tf < 2; ++tf)
      #pragma unroll
      for (int nf = 0; nf < 2; ++nf)
        acc1[tf][nf] = f32x4{b1v[nf], b1v[nf], b1v[nf], b1v[nf]};

    int nt0 = hq*64 + it*16 + w*2;

    #pragma unroll
    for (int jr = 0; jr < 8; ++jr){
      int j = 7 - jr;                    // reverse K-block order -> suffix sums
      // GEMM1: 4 kt steps, 2A x 2B -> 4 MFMA each
      #pragma unroll
      for (int s = 0; s < 4; ++s){
        int kt = j*4 + s;
        half8 a0  = *reinterpret_cast<const half8*>(xb0 + (size_t)kt*512);
        half8 a1  = *reinterpret_cast<const half8*>(xb1 + (size_t)kt*512);
        half8 bb0 = *reinterpret_cast<const half8*>(w1t + ((size_t)kt*256 + nt0    )*512 + lane*8);
        half8 bb1 = *reinterpret_cast<const half8*>(w1t + ((size_t)kt*256 + nt0 + 1)*512 + lane*8);
        acc1[0][0] = __builtin_amdgcn_mfma_f32_16x16x32_f16(a0, bb0, acc1[0][0], 0,0,0);
        acc1[0][1] = __builtin_amdgcn_mfma_f32_16x16x32_f16(a0, bb1, acc1[0][1], 0,0,0);
        acc1[1][0] = __builtin_amdgcn_mfma_f32_16x16x32_f16(a1, bb0, acc1[1][0], 0,0,0);
        acc1[1][1] = __builtin_amdgcn_mfma_f32_16x16x32_f16(a1, bb1, acc1[1][1], 0,0,0);
      }
      // snapshot -> gelu -> swizzled frag-order LDS write (4-way conflicts)
      _Float16* pb = Pbuf + (jr & 1)*8192;
      #pragma unroll
      for (int tf = 0; tf < 2; ++tf)
        #pragma unroll
        for (int nf = 0; nf < 2; ++nf)
          #pragma unroll
          for (int i = 0; i < 4; ++i){
            float v = gelu_f(acc1[tf][nf][i]);
            int L  = (q*4 + i) + 16*(nf*2 + m16h);
            int Ls = L ^ (((L >> 4) & 3) << 1);
            pb[(size_t)((tf*8 + w)*64 + Ls)*8 + m16l] = (_Float16)v;
          }
      __syncthreads();                   // one barrier/level (double-buffered)
      // GEMM2: wave (tg, rs): 16tok x 32R, K = 256 (8 kf frags from LDS)
      const _Float16* rb = Pbuf + (jr & 1)*8192;
      #pragma unroll
      for (int kf = 0; kf < 8; ++kf){
        half8 a2 = *reinterpret_cast<const half8*>(rb + (size_t)((tg*8 + kf)*64 + lsw)*8);
        outA[j][0] = __builtin_amdgcn_mfma_f32_16x16x32_f16(a2, w2f[kf][0], outA[j][0], 0,0,0);
        outA[j][1] = __builtin_amdgcn_mfma_f32_16x16x32_f16(a2, w2f[kf][1], outA[j][1], 0,0,0);
      }
    }
  }

  // combine 4 H-quarters: atomicAdd onto b2-initialized d_out
  float* ob = out + (size_t)(tt*32 + tg*16 + q*4)*1024 + rs*32 + m16;
  #pragma unroll
  for (int j = 0; j < 8; ++j)
    #pragma unroll
    for (int t = 0; t < 2; ++t)
      #pragma unroll
      for (int i = 0; i < 4; ++i)
        atomicAdd(&ob[i*1024 + j*128 + t*16], outA[j][t][i]);
}

extern "C" void kernel_launch(void* const* d_in, const int* in_sizes, int n_in,
                              void* d_out, int out_size, void* d_ws, size_t ws_size,
                              hipStream_t stream){
  (void)in_sizes; (void)n_in; (void)out_size; (void)ws_size;
  const float* x  = (const float*)d_in[0];
  const float* W1 = (const float*)d_in[1];
  const float* b1 = (const float*)d_in[2];
  const float* W2 = (const float*)d_in[3];
  const float* b2 = (const float*)d_in[4];
  float* out = (float*)d_out;

  _Float16* xt  = (_Float16*)d_ws;
  _Float16* w1t = xt  + 4194304;
  _Float16* w2t = w1t + 4194304;

  hipLaunchKernelGGL(k_prep, dim3(8448), dim3(256), 0, stream,
                     x, W1, W2, b2, xt, w1t, w2t, out);
  hipLaunchKernelGGL(k_treemlp, dim3(512), dim3(512), 0, stream,
                     xt, w1t, w2t, b1, out);
}

// Round 3
// 384.274 us; speedup vs baseline: 1.1851x; 1.0395x over previous
//
#include <hip/hip_runtime.h>
#include <hip/hip_bf16.h>

// TreeMLP fused kernel for MI355X (gfx950), round 3.
//
// pre_l = b1 + sum_{j>=l} x_blockj @ W1_blockj  -> reverse-order K-loop with
// snapshots; GEMM2 fused per snapshot. R3 changes vs R2:
//  - NO atomics: blocks write fp32 partial tiles to ws; k_reduce sums 4
//    H-quarter partials + b2 into d_out (atomic RMW tail was the R2 wall)
//  - GEMM2 software-pipelined one level behind GEMM1 (fills load latency)
//  - out-init removed from critical path (b2 applied in k_reduce)
//
// ws layout:
//   xt : fp16 [256 t16][32 kt][64 lane][8]      8 MB   (A-frag order)
//   w1t: fp16 [32 kt][256 nt][64 lane][8]       8 MB   (B-frag order)
//   w2t: fp16 [128 kt2][8 ntr][64 lane][8]      1 MB   (B-frag order)
//   partial: fp32 [4 hq][4096 tok][8 lev][128]  64 MB
// total 84,934,656 B.  Fallback to R2 atomic path if ws_size too small.

typedef _Float16 half8 __attribute__((ext_vector_type(8)));
typedef float    f32x4 __attribute__((ext_vector_type(4)));

#define EDIM 1024
#define HDIM 4096
#define RDIM 128

__device__ __forceinline__ float gelu_f(float x){
  // 0.5x(1+tanh(c(x+0.044715x^3))) == x * sigmoid(x*(2c + 2c*0.044715*x^2))
  float t2 = x * fmaf(x*x, 0.07135481283840494f, 1.5957691216057308f);
  float e  = __expf(-t2);
  return x * __builtin_amdgcn_rcpf(1.0f + e);
}

// ---- fused prep: cast fp32->fp16 into MFMA fragment lane order ----
__global__ void k_prep(const float* __restrict__ x, const float* __restrict__ w1,
                       const float* __restrict__ w2,
                       _Float16* __restrict__ xt, _Float16* __restrict__ w1t,
                       _Float16* __restrict__ w2t){
  int bid = blockIdx.x;
  if (bid < 2048){                                   // xt
    int tid = bid*256 + threadIdx.x;
    int lane = tid & 63;
    int kt   = (tid >> 6) & 31;
    int t16  = tid >> 11;
    int m = lane & 15, kq = lane >> 4;
    const float4* s4 = reinterpret_cast<const float4*>(x + (size_t)(t16*16 + m)*EDIM + kt*32 + kq*8);
    float4 a = s4[0], b = s4[1];
    half8 v;
    v[0]=(_Float16)a.x; v[1]=(_Float16)a.y; v[2]=(_Float16)a.z; v[3]=(_Float16)a.w;
    v[4]=(_Float16)b.x; v[5]=(_Float16)b.y; v[6]=(_Float16)b.z; v[7]=(_Float16)b.w;
    *reinterpret_cast<half8*>(xt + (size_t)tid*8) = v;
  } else if (bid < 4096){                            // w1t
    int tid = (bid - 2048)*256 + threadIdx.x;
    int lane = tid & 63;
    int tile = tid >> 6;
    int nt = tile & 255, kt = tile >> 8;
    int n = nt*16 + (lane & 15);
    int k = kt*32 + (lane >> 4)*8;
    const float* src = w1 + (size_t)k*HDIM + n;
    half8 v;
    #pragma unroll
    for (int jj = 0; jj < 8; ++jj) v[jj] = (_Float16)src[(size_t)jj*HDIM];
    *reinterpret_cast<half8*>(w1t + (size_t)tid*8) = v;
  } else {                                           // w2t
    int tid = (bid - 4096)*256 + threadIdx.x;
    int lane = tid & 63;
    int tile = tid >> 6;
    int ntr = tile & 7, kt2 = tile >> 3;
    int n = ntr*16 + (lane & 15);
    int k = kt2*32 + (lane >> 4)*8;
    const float* src = w2 + (size_t)k*RDIM + n;
    half8 v;
    #pragma unroll
    for (int jj = 0; jj < 8; ++jj) v[jj] = (_Float16)src[(size_t)jj*RDIM];
    *reinterpret_cast<half8*>(w2t + (size_t)tid*8) = v;
  }
}

__global__ void k_init_out(const float* __restrict__ b2, float* __restrict__ out){
  int i = blockIdx.x*256 + threadIdx.x;              // 1048576 float4s
  float4 bv = reinterpret_cast<const float4*>(b2)[i & 31];
  reinterpret_cast<float4*>(out)[i] = bv;
}

// ---- reduce: out = b2 + sum over 4 H-quarter partials ----
__global__ void k_reduce(const float* __restrict__ partial, const float* __restrict__ b2,
                         float* __restrict__ out){
  int i = blockIdx.x*256 + threadIdx.x;              // 1048576 float4s
  const float4* p4 = reinterpret_cast<const float4*>(partial);
  float4 bv = reinterpret_cast<const float4*>(b2)[i & 31];
  float4 a = p4[i], b = p4[i + 1048576], c = p4[i + 2097152], d = p4[i + 3145728];
  float4 r;
  r.x = bv.x + (a.x + b.x) + (c.x + d.x);
  r.y = bv.y + (a.y + b.y) + (c.y + d.y);
  r.z = bv.z + (a.z + b.z) + (c.z + d.z);
  r.w = bv.w + (a.w + b.w) + (c.w + d.w);
  reinterpret_cast<float4*>(out)[i] = r;
}

// ---- main fused kernel ----
// grid 512 x 512 thr (8 waves). block = (token tile of 32) x (H-quarter 1024).
// hq = (b&7)>>1 so each XCD touches ONE 2MB W1-quarter (L2-resident).
// Per h-tile of 256 cols (4 its): W2 regs hoisted; K reversed j=7..0.
// Pipeline: body jr does GEMM2(level jr-1) interleaved with GEMM1(level jr),
// then gelu -> swizzled LDS -> barrier; epilogue GEMM2(level 7's data = j0).
__global__ __launch_bounds__(512, 2) void k_treemlp(
    const _Float16* __restrict__ xt, const _Float16* __restrict__ w1t,
    const _Float16* __restrict__ w2t, const float* __restrict__ b1,
    float* __restrict__ partial, float* __restrict__ out, int use_partial){
  int b    = blockIdx.x;
  int hq   = (b & 7) >> 1;              // H-quarter, constant per XCD
  int tt   = (b >> 3)*2 + (b & 1);      // token tile 0..127
  int w    = threadIdx.x >> 6;          // wave 0..7
  int lane = threadIdx.x & 63;
  int m16 = lane & 15, q = lane >> 4;
  int m16h = m16 >> 3, m16l = m16 & 7;
  int tg = w >> 2, rs = w & 3;          // GEMM2 roles
  int lsw = lane ^ (((lane >> 4) & 3) << 1);   // swizzled LDS read lane

  __shared__ _Float16 Pbuf[2*16*64*8];  // double-buffered P, frag order, 32 KB

  f32x4 outA[8][2];
  #pragma unroll
  for (int j = 0; j < 8; ++j){
    outA[j][0] = f32x4{0.f,0.f,0.f,0.f};
    outA[j][1] = f32x4{0.f,0.f,0.f,0.f};
  }

  const _Float16* xb0 = xt + (size_t)(tt*2 + 0)*16384 + lane*8;   // + kt*512
  const _Float16* xb1 = xt + (size_t)(tt*2 + 1)*16384 + lane*8;

  for (int it = 0; it < 4; ++it){
    // hoist W2 fragments for this 256-col h-tile (jr-invariant): 16 frags
    half8 w2f[8][2];
    #pragma unroll
    for (int s = 0; s < 8; ++s)
      #pragma unroll
      for (int t = 0; t < 2; ++t)
        w2f[s][t] = *reinterpret_cast<const half8*>(
            w2t + (size_t)(((hq*32 + it*8 + s)*8) + rs*2 + t)*512 + lane*8);

    // acc1 initialized with b1 (snapshots are pre-activation directly)
    float b1v[2];
    #pragma unroll
    for (int nf = 0; nf < 2; ++nf)
      b1v[nf] = b1[hq*1024 + it*256 + w*32 + nf*16 + m16];
    f32x4 acc1[2][2];
    #pragma unroll
    for (int tf = 0; tf < 2; ++tf)
      #pragma unroll
      for (int nf = 0; nf < 2; ++nf)
        acc1[tf][nf] = f32x4{b1v[nf], b1v[nf], b1v[nf], b1v[nf]};

    int nt0 = hq*64 + it*16 + w*2;

    #pragma unroll
    for (int jr = 0; jr < 8; ++jr){
      int j = 7 - jr;                    // reverse K-block order -> suffix sums

      // GEMM2 for PREVIOUS level (pipelined; independent of this GEMM1)
      if (jr > 0){
        int jp = j + 1;
        const _Float16* rb = Pbuf + ((jr-1) & 1)*8192;
        #pragma unroll
        for (int kf = 0; kf < 8; ++kf){
          half8 a2 = *reinterpret_cast<const half8*>(rb + (size_t)((tg*8 + kf)*64 + lsw)*8);
          outA[jp][0] = __builtin_amdgcn_mfma_f32_16x16x32_f16(a2, w2f[kf][0], outA[jp][0], 0,0,0);
          outA[jp][1] = __builtin_amdgcn_mfma_f32_16x16x32_f16(a2, w2f[kf][1], outA[jp][1], 0,0,0);
        }
      }

      // GEMM1: 4 kt steps, 2A x 2B -> 4 MFMA each
      #pragma unroll
      for (int s = 0; s < 4; ++s){
        int kt = j*4 + s;
        half8 a0  = *reinterpret_cast<const half8*>(xb0 + (size_t)kt*512);
        half8 a1  = *reinterpret_cast<const half8*>(xb1 + (size_t)kt*512);
        half8 bb0 = *reinterpret_cast<const half8*>(w1t + ((size_t)kt*256 + nt0    )*512 + lane*8);
        half8 bb1 = *reinterpret_cast<const half8*>(w1t + ((size_t)kt*256 + nt0 + 1)*512 + lane*8);
        acc1[0][0] = __builtin_amdgcn_mfma_f32_16x16x32_f16(a0, bb0, acc1[0][0], 0,0,0);
        acc1[0][1] = __builtin_amdgcn_mfma_f32_16x16x32_f16(a0, bb1, acc1[0][1], 0,0,0);
        acc1[1][0] = __builtin_amdgcn_mfma_f32_16x16x32_f16(a1, bb0, acc1[1][0], 0,0,0);
        acc1[1][1] = __builtin_amdgcn_mfma_f32_16x16x32_f16(a1, bb1, acc1[1][1], 0,0,0);
      }

      // snapshot -> gelu -> swizzled frag-order LDS write
      _Float16* pb = Pbuf + (jr & 1)*8192;
      #pragma unroll
      for (int tf = 0; tf < 2; ++tf)
        #pragma unroll
        for (int nf = 0; nf < 2; ++nf)
          #pragma unroll
          for (int i = 0; i < 4; ++i){
            float v = gelu_f(acc1[tf][nf][i]);
            int L  = (q*4 + i) + 16*(nf*2 + m16h);
            int Ls = L ^ (((L >> 4) & 3) << 1);
            pb[(size_t)((tf*8 + w)*64 + Ls)*8 + m16l] = (_Float16)v;
          }
      __syncthreads();
    }
    // epilogue GEMM2 for level j=0 (written at jr=7 into buf 1)
    {
      const _Float16* rb = Pbuf + 8192;
      #pragma unroll
      for (int kf = 0; kf < 8; ++kf){
        half8 a2 = *reinterpret_cast<const half8*>(rb + (size_t)((tg*8 + kf)*64 + lsw)*8);
        outA[0][0] = __builtin_amdgcn_mfma_f32_16x16x32_f16(a2, w2f[kf][0], outA[0][0], 0,0,0);
        outA[0][1] = __builtin_amdgcn_mfma_f32_16x16x32_f16(a2, w2f[kf][1], outA[0][1], 0,0,0);
      }
    }
  }

  if (use_partial){
    // coalesced fp32 partial stores: partial[hq][tok][lev][128]
    float* ob = partial + (size_t)hq*4194304
              + (size_t)(tt*32 + tg*16 + q*4)*1024 + rs*32 + m16;
    #pragma unroll
    for (int j = 0; j < 8; ++j)
      #pragma unroll
      for (int t = 0; t < 2; ++t)
        #pragma unroll
        for (int i = 0; i < 4; ++i)
          ob[i*1024 + j*128 + t*16] = outA[j][t][i];
  } else {
    float* ob = out + (size_t)(tt*32 + tg*16 + q*4)*1024 + rs*32 + m16;
    #pragma unroll
    for (int j = 0; j < 8; ++j)
      #pragma unroll
      for (int t = 0; t < 2; ++t)
        #pragma unroll
        for (int i = 0; i < 4; ++i)
          atomicAdd(&ob[i*1024 + j*128 + t*16], outA[j][t][i]);
  }
}

extern "C" void kernel_launch(void* const* d_in, const int* in_sizes, int n_in,
                              void* d_out, int out_size, void* d_ws, size_t ws_size,
                              hipStream_t stream){
  (void)in_sizes; (void)n_in; (void)out_size;
  const float* x  = (const float*)d_in[0];
  const float* W1 = (const float*)d_in[1];
  const float* b1 = (const float*)d_in[2];
  const float* W2 = (const float*)d_in[3];
  const float* b2 = (const float*)d_in[4];
  float* out = (float*)d_out;

  _Float16* xt  = (_Float16*)d_ws;
  _Float16* w1t = xt  + 4194304;
  _Float16* w2t = w1t + 4194304;
  float* partial = (float*)(w2t + 524288);   // 64 MB fp32
  const size_t need = (size_t)(4194304 + 4194304 + 524288)*2 + (size_t)16777216*4;
  int use_partial = (ws_size >= need) ? 1 : 0;

  hipLaunchKernelGGL(k_prep, dim3(4352), dim3(256), 0, stream, x, W1, W2, xt, w1t, w2t);
  if (!use_partial)
    hipLaunchKernelGGL(k_init_out, dim3(4096), dim3(256), 0, stream, b2, out);
  hipLaunchKernelGGL(k_treemlp, dim3(512), dim3(512), 0, stream,
                     xt, w1t, w2t, b1, partial, out, use_partial);
  if (use_partial)
    hipLaunchKernelGGL(k_reduce, dim3(4096), dim3(256), 0, stream, partial, b2, out);
}

// Round 4
// 300.994 us; speedup vs baseline: 1.5130x; 1.2767x over previous
//
#include <hip/hip_runtime.h>
#include <hip/hip_bf16.h>

// TreeMLP fused kernel for MI355X (gfx950), round 4.
//
// pre_l = b1 + sum_{j>=l} x_blockj @ W1_blockj  -> reverse-order K-loop with
// snapshots; GEMM2 fused per snapshot. R4 changes vs R3:
//  - GEMM1 computes P^T (MFMA operands swapped): lane's 4 C-values = 4
//    contiguous hcols -> half4 pack -> 4x ds_write_b64 (was 16x ds_write_b16);
//    GEMM2 A-frags = ds_read_b128 from [tok][hcol] padded scratch
//  - H-EIGHTH split (hq = b&7, grid 1024): per-XCD W1 slice 1MB -> fits L2
//    with live xt tiles (R3 thrashed: 450MB L2-miss traffic)
//  - fp16 packed partials (67MB) + nontemporal stores/loads (no write-alloc)
//  - no w2f register hoist; __launch_bounds__(512,4) targets 2 blocks/CU
//
// ws layout:
//   xt : fp16 [256 t16][32 kt][64 lane][8]      8 MB   (frag order)
//   w1t: fp16 [32 kt][256 nt][64 lane][8]       8 MB   (frag order)
//   w2t: fp16 [128 kt2][8 ntr][64 lane][8]      1 MB   (frag order)
//   partial: u32 [8 hq][4096 tok][8 lev][4 rs][16 m16]{2 half}  64 MB
// total 84,934,656 B (same as R3's proven-available need).

typedef _Float16 half8 __attribute__((ext_vector_type(8)));
typedef _Float16 half4 __attribute__((ext_vector_type(4)));
typedef _Float16 half2v __attribute__((ext_vector_type(2)));
typedef float    f32x4 __attribute__((ext_vector_type(4)));

#define EDIM 1024
#define HDIM 4096
#define RDIM 128
#define PROW 264   // scratch row stride in halves (256 + 8 pad; keeps 16B align)

__device__ __forceinline__ float gelu_f(float x){
  // 0.5x(1+tanh(c(x+0.044715x^3))) == x * sigmoid(x*(2c + 2c*0.044715*x^2))
  float t2 = x * fmaf(x*x, 0.07135481283840494f, 1.5957691216057308f);
  float e  = __expf(-t2);
  return x * __builtin_amdgcn_rcpf(1.0f + e);
}

// ---- fused prep: cast fp32->fp16 into MFMA fragment lane order ----
__global__ void k_prep(const float* __restrict__ x, const float* __restrict__ w1,
                       const float* __restrict__ w2,
                       _Float16* __restrict__ xt, _Float16* __restrict__ w1t,
                       _Float16* __restrict__ w2t){
  int bid = blockIdx.x;
  if (bid < 2048){                                   // xt
    int tid = bid*256 + threadIdx.x;
    int lane = tid & 63;
    int kt   = (tid >> 6) & 31;
    int t16  = tid >> 11;
    int m = lane & 15, kq = lane >> 4;
    const float4* s4 = reinterpret_cast<const float4*>(x + (size_t)(t16*16 + m)*EDIM + kt*32 + kq*8);
    float4 a = s4[0], b = s4[1];
    half8 v;
    v[0]=(_Float16)a.x; v[1]=(_Float16)a.y; v[2]=(_Float16)a.z; v[3]=(_Float16)a.w;
    v[4]=(_Float16)b.x; v[5]=(_Float16)b.y; v[6]=(_Float16)b.z; v[7]=(_Float16)b.w;
    *reinterpret_cast<half8*>(xt + (size_t)tid*8) = v;
  } else if (bid < 4096){                            // w1t
    int tid = (bid - 2048)*256 + threadIdx.x;
    int lane = tid & 63;
    int tile = tid >> 6;
    int nt = tile & 255, kt = tile >> 8;
    int n = nt*16 + (lane & 15);
    int k = kt*32 + (lane >> 4)*8;
    const float* src = w1 + (size_t)k*HDIM + n;
    half8 v;
    #pragma unroll
    for (int jj = 0; jj < 8; ++jj) v[jj] = (_Float16)src[(size_t)jj*HDIM];
    *reinterpret_cast<half8*>(w1t + (size_t)tid*8) = v;
  } else {                                           // w2t
    int tid = (bid - 4096)*256 + threadIdx.x;
    int lane = tid & 63;
    int tile = tid >> 6;
    int ntr = tile & 7, kt2 = tile >> 3;
    int n = ntr*16 + (lane & 15);
    int k = kt2*32 + (lane >> 4)*8;
    const float* src = w2 + (size_t)k*RDIM + n;
    half8 v;
    #pragma unroll
    for (int jj = 0; jj < 8; ++jj) v[jj] = (_Float16)src[(size_t)jj*RDIM];
    *reinterpret_cast<half8*>(w2t + (size_t)tid*8) = v;
  }
}

__global__ void k_init_out(const float* __restrict__ b2, float* __restrict__ out){
  int i = blockIdx.x*256 + threadIdx.x;              // 1048576 float4s
  float4 bv = reinterpret_cast<const float4*>(b2)[i & 31];
  reinterpret_cast<float4*>(out)[i] = bv;
}

// ---- reduce: out = b2 + sum over 8 H-eighth fp16 partials ----
__global__ void k_reduce(const unsigned* __restrict__ part, const float* __restrict__ b2,
                         float* __restrict__ out){
  int tid = blockIdx.x*256 + threadIdx.x;            // 0..2097151
  int m16 = tid & 15, rs = (tid >> 4) & 3, j = (tid >> 6) & 7, tok = tid >> 9;
  float s0 = 0.f, s1 = 0.f;
  #pragma unroll
  for (int hq = 0; hq < 8; ++hq){
    unsigned v = __builtin_nontemporal_load(part + (size_t)hq*2097152 + tid);
    half2v h = __builtin_bit_cast(half2v, v);
    s0 += (float)h[0];
    s1 += (float)h[1];
  }
  int r0 = rs*32 + m16;
  size_t ob = (size_t)tok*1024 + j*128 + r0;
  out[ob]      = s0 + b2[r0];
  out[ob + 16] = s1 + b2[r0 + 16];
}

// ---- main fused kernel ----
// grid 1024 x 512 thr (8 waves). block = (token tile of 32) x (H-eighth 512).
// hq = b&7 == XCD id -> per-XCD W1 slice 1MB, L2-resident.
// 2 its of 256 hcols. GEMM1 transposed (A=w1 frag, B=x frag -> C rows=hcols).
// Pipeline: jr body does GEMM2(level jr-1) then GEMM1(level jr), gelu ->
// b64 LDS writes -> barrier; per-it epilogue GEMM2(level 0's data).
__global__ __launch_bounds__(512, 4) void k_treemlp(
    const _Float16* __restrict__ xt, const _Float16* __restrict__ w1t,
    const _Float16* __restrict__ w2t, const float* __restrict__ b1,
    unsigned* __restrict__ partial, float* __restrict__ out, int use_partial){
  int b    = blockIdx.x;
  int hq   = b & 7;                     // H-eighth == XCD slot
  int tt   = b >> 3;                    // token tile 0..127
  int w    = threadIdx.x >> 6;          // wave 0..7
  int lane = threadIdx.x & 63;
  int m16 = lane & 15, q = lane >> 4;
  int tg = w >> 2, rs = w & 3;          // GEMM2 roles

  __shared__ _Float16 Pbuf[2*32*PROW];  // double-buffered P^T scratch, 33 KB

  f32x4 outA[8][2];
  #pragma unroll
  for (int j = 0; j < 8; ++j){
    outA[j][0] = f32x4{0.f,0.f,0.f,0.f};
    outA[j][1] = f32x4{0.f,0.f,0.f,0.f};
  }

  const _Float16* xb0 = xt + (size_t)(tt*2 + 0)*16384 + lane*8;   // + kt*512
  const _Float16* xb1 = xt + (size_t)(tt*2 + 1)*16384 + lane*8;

  #pragma unroll
  for (int it = 0; it < 2; ++it){
    // b1 slice for this wave's 32 hcols (4 contiguous per lane per hf)
    f32x4 b1v[2];
    #pragma unroll
    for (int hf = 0; hf < 2; ++hf){
      float4 bv = *reinterpret_cast<const float4*>(
          b1 + hq*512 + it*256 + w*32 + hf*16 + q*4);
      b1v[hf] = f32x4{bv.x, bv.y, bv.z, bv.w};
    }
    // acc1[hf][tf2]: C^T accums (rows=hcols, cols=tokens); init with b1
    f32x4 acc1[2][2];
    #pragma unroll
    for (int hf = 0; hf < 2; ++hf)
      #pragma unroll
      for (int tf = 0; tf < 2; ++tf)
        acc1[hf][tf] = b1v[hf];

    int ntb = hq*32 + it*16 + w*2;                       // w1t nt base
    const _Float16* w2p = w2t + ((size_t)(hq*16 + it*8)*8 + rs*2)*512 + lane*8;

    #pragma unroll
    for (int jr = 0; jr < 8; ++jr){
      int j = 7 - jr;                    // reverse K-block order -> suffix sums

      // GEMM2 for PREVIOUS level (pipelined; independent of this GEMM1)
      if (jr > 0){
        int jp = j + 1;
        const _Float16* rb = Pbuf + ((jr-1) & 1)*(32*PROW) + (size_t)(tg*16 + m16)*PROW + q*8;
        #pragma unroll
        for (int kf = 0; kf < 8; ++kf){
          half8 a2 = *reinterpret_cast<const half8*>(rb + kf*32);
          half8 bw0 = *reinterpret_cast<const half8*>(w2p + (size_t)kf*4096);
          half8 bw1 = *reinterpret_cast<const half8*>(w2p + (size_t)kf*4096 + 512);
          outA[jp][0] = __builtin_amdgcn_mfma_f32_16x16x32_f16(a2, bw0, outA[jp][0], 0,0,0);
          outA[jp][1] = __builtin_amdgcn_mfma_f32_16x16x32_f16(a2, bw1, outA[jp][1], 0,0,0);
        }
      }

      // GEMM1 (transposed): 4 kt steps, A=w1 frags (2 hf) x B=x frags (2 tf)
      #pragma unroll
      for (int s = 0; s < 4; ++s){
        int kt = j*4 + s;
        half8 aw0 = *reinterpret_cast<const half8*>(w1t + ((size_t)kt*256 + ntb    )*512 + lane*8);
        half8 aw1 = *reinterpret_cast<const half8*>(w1t + ((size_t)kt*256 + ntb + 1)*512 + lane*8);
        half8 bx0 = *reinterpret_cast<const half8*>(xb0 + (size_t)kt*512);
        half8 bx1 = *reinterpret_cast<const half8*>(xb1 + (size_t)kt*512);
        acc1[0][0] = __builtin_amdgcn_mfma_f32_16x16x32_f16(aw0, bx0, acc1[0][0], 0,0,0);
        acc1[0][1] = __builtin_amdgcn_mfma_f32_16x16x32_f16(aw0, bx1, acc1[0][1], 0,0,0);
        acc1[1][0] = __builtin_amdgcn_mfma_f32_16x16x32_f16(aw1, bx0, acc1[1][0], 0,0,0);
        acc1[1][1] = __builtin_amdgcn_mfma_f32_16x16x32_f16(aw1, bx1, acc1[1][1], 0,0,0);
      }

      // snapshot -> gelu -> half4 pack -> b64 LDS write into [tok][hcol]
      _Float16* pb = Pbuf + (jr & 1)*(32*PROW);
      #pragma unroll
      for (int hf = 0; hf < 2; ++hf)
        #pragma unroll
        for (int tf = 0; tf < 2; ++tf){
          half4 hv;
          #pragma unroll
          for (int i = 0; i < 4; ++i)
            hv[i] = (_Float16)gelu_f(acc1[hf][tf][i]);
          int tok  = tf*16 + m16;
          int hcol = w*32 + hf*16 + q*4;
          *reinterpret_cast<half4*>(pb + (size_t)tok*PROW + hcol) = hv;
        }
      __syncthreads();
    }
    // per-it epilogue: GEMM2 for level 0 (written at jr=7 into buf 1)
    {
      const _Float16* rb = Pbuf + (32*PROW) + (size_t)(tg*16 + m16)*PROW + q*8;
      #pragma unroll
      for (int kf = 0; kf < 8; ++kf){
        half8 a2 = *reinterpret_cast<const half8*>(rb + kf*32);
        half8 bw0 = *reinterpret_cast<const half8*>(w2p + (size_t)kf*4096);
        half8 bw1 = *reinterpret_cast<const half8*>(w2p + (size_t)kf*4096 + 512);
        outA[0][0] = __builtin_amdgcn_mfma_f32_16x16x32_f16(a2, bw0, outA[0][0], 0,0,0);
        outA[0][1] = __builtin_amdgcn_mfma_f32_16x16x32_f16(a2, bw1, outA[0][1], 0,0,0);
      }
    }
  }

  int tokb = tt*32 + tg*16 + q*4;
  if (use_partial){
    // packed fp16 partial: u32[hq][tok][lev][rs][m16] = {t0,t1} halves
    unsigned* pb = partial + (size_t)hq*2097152 + (size_t)tokb*512 + rs*16 + m16;
    #pragma unroll
    for (int j = 0; j < 8; ++j)
      #pragma unroll
      for (int i = 0; i < 4; ++i){
        half2v p;
        p[0] = (_Float16)outA[j][0][i];
        p[1] = (_Float16)outA[j][1][i];
        __builtin_nontemporal_store(__builtin_bit_cast(unsigned, p),
                                    pb + (size_t)i*512 + j*64);
      }
  } else {
    float* ob = out + (size_t)tokb*1024 + rs*32 + m16;
    #pragma unroll
    for (int j = 0; j < 8; ++j)
      #pragma unroll
      for (int t = 0; t < 2; ++t)
        #pragma unroll
        for (int i = 0; i < 4; ++i)
          atomicAdd(&ob[i*1024 + j*128 + t*16], outA[j][t][i]);
  }
}

extern "C" void kernel_launch(void* const* d_in, const int* in_sizes, int n_in,
                              void* d_out, int out_size, void* d_ws, size_t ws_size,
                              hipStream_t stream){
  (void)in_sizes; (void)n_in; (void)out_size;
  const float* x  = (const float*)d_in[0];
  const float* W1 = (const float*)d_in[1];
  const float* b1 = (const float*)d_in[2];
  const float* W2 = (const float*)d_in[3];
  const float* b2 = (const float*)d_in[4];
  float* out = (float*)d_out;

  _Float16* xt  = (_Float16*)d_ws;
  _Float16* w1t = xt  + 4194304;
  _Float16* w2t = w1t + 4194304;
  unsigned* partial = (unsigned*)(w2t + 524288);   // 64 MB packed fp16
  const size_t need = (size_t)(4194304 + 4194304 + 524288)*2 + (size_t)16777216*4;
  int use_partial = (ws_size >= need) ? 1 : 0;

  hipLaunchKernelGGL(k_prep, dim3(4352), dim3(256), 0, stream, x, W1, W2, xt, w1t, w2t);
  if (!use_partial)
    hipLaunchKernelGGL(k_init_out, dim3(4096), dim3(256), 0, stream, b2, out);
  hipLaunchKernelGGL(k_treemlp, dim3(1024), dim3(512), 0, stream,
                     xt, w1t, w2t, b1, partial, out, use_partial);
  if (use_partial)
    hipLaunchKernelGGL(k_reduce, dim3(8192), dim3(256), 0, stream, partial, b2, out);
}

// Round 5
// 244.381 us; speedup vs baseline: 1.8635x; 1.2317x over previous
//
#include <hip/hip_runtime.h>
#include <hip/hip_bf16.h>

// TreeMLP fused kernel for MI355X (gfx950), round 5.
//
// pre_l = b1 + sum_{j>=l} x_blockj @ W1_blockj  -> reverse-order K-loop with
// snapshots; GEMM2 fused per snapshot. R5 changes vs R4:
//  - LEVEL LOOP OUTERMOST: per level j, GEMM1 adds 4 kt for BOTH H-halves
//    (x frags shared), then GEMM2 runs full K=512 for level j immediately.
//    outA: 64 regs -> 8 (outJ), freeing space to...
//  - hoist ALL 16 W2 fragments per wave for the whole kernel (R4 re-read
//    w2 every jr from L1/L2: ~2 GB device-wide, the dominant VMEM stream)
//  - partial layout [hq][tt][j][i][rr][q][m16]: each wave store = contiguous
//    256 B (R4's q-interleaved 64 B segments caused 2.5x write amplification)
//
// ws layout:
//   xt : fp16 [256 t16][32 kt][64 lane][8]      8 MB   (A/B frag order)
//   w1t: fp16 [32 kt][256 nt][64 lane][8]       8 MB   (frag order)
//   w2t: fp16 [128 kt2][8 ntr][64 lane][8]      1 MB   (frag order)
//   partial: u32 [8 hq][128 tt][8 j][4 i][8 rr][4 q][16 m16]  64 MB
// total 84,934,656 B.

typedef _Float16 half8 __attribute__((ext_vector_type(8)));
typedef _Float16 half4 __attribute__((ext_vector_type(4)));
typedef _Float16 half2v __attribute__((ext_vector_type(2)));
typedef float    f32x4 __attribute__((ext_vector_type(4)));

#define EDIM 1024
#define HDIM 4096
#define RDIM 128
#define PROW 264   // P^T scratch row stride in halves (256 + 8 pad)

#define MFMA16(A,B,C) __builtin_amdgcn_mfma_f32_16x16x32_f16(A, B, C, 0, 0, 0)

__device__ __forceinline__ float gelu_f(float x){
  // 0.5x(1+tanh(c(x+0.044715x^3))) == x * sigmoid(x*(2c + 2c*0.044715*x^2))
  // folded with log2(e) so we can use exp2 directly
  float t2 = x * fmaf(x*x, 0.10294324f, 2.30220842f);
  float e  = __builtin_amdgcn_exp2f(-t2);
  return x * __builtin_amdgcn_rcpf(1.0f + e);
}

// ---- fused prep: cast fp32->fp16 into MFMA fragment lane order ----
__global__ void k_prep(const float* __restrict__ x, const float* __restrict__ w1,
                       const float* __restrict__ w2,
                       _Float16* __restrict__ xt, _Float16* __restrict__ w1t,
                       _Float16* __restrict__ w2t){
  int bid = blockIdx.x;
  if (bid < 2048){                                   // xt
    int tid = bid*256 + threadIdx.x;
    int lane = tid & 63;
    int kt   = (tid >> 6) & 31;
    int t16  = tid >> 11;
    int m = lane & 15, kq = lane >> 4;
    const float4* s4 = reinterpret_cast<const float4*>(x + (size_t)(t16*16 + m)*EDIM + kt*32 + kq*8);
    float4 a = s4[0], b = s4[1];
    half8 v;
    v[0]=(_Float16)a.x; v[1]=(_Float16)a.y; v[2]=(_Float16)a.z; v[3]=(_Float16)a.w;
    v[4]=(_Float16)b.x; v[5]=(_Float16)b.y; v[6]=(_Float16)b.z; v[7]=(_Float16)b.w;
    *reinterpret_cast<half8*>(xt + (size_t)tid*8) = v;
  } else if (bid < 4096){                            // w1t
    int tid = (bid - 2048)*256 + threadIdx.x;
    int lane = tid & 63;
    int tile = tid >> 6;
    int nt = tile & 255, kt = tile >> 8;
    int n = nt*16 + (lane & 15);
    int k = kt*32 + (lane >> 4)*8;
    const float* src = w1 + (size_t)k*HDIM + n;
    half8 v;
    #pragma unroll
    for (int jj = 0; jj < 8; ++jj) v[jj] = (_Float16)src[(size_t)jj*HDIM];
    *reinterpret_cast<half8*>(w1t + (size_t)tid*8) = v;
  } else {                                           // w2t
    int tid = (bid - 4096)*256 + threadIdx.x;
    int lane = tid & 63;
    int tile = tid >> 6;
    int ntr = tile & 7, kt2 = tile >> 3;
    int n = ntr*16 + (lane & 15);
    int k = kt2*32 + (lane >> 4)*8;
    const float* src = w2 + (size_t)k*RDIM + n;
    half8 v;
    #pragma unroll
    for (int jj = 0; jj < 8; ++jj) v[jj] = (_Float16)src[(size_t)jj*RDIM];
    *reinterpret_cast<half8*>(w2t + (size_t)tid*8) = v;
  }
}

__global__ void k_init_out(const float* __restrict__ b2, float* __restrict__ out){
  int i = blockIdx.x*256 + threadIdx.x;              // 1048576 float4s
  float4 bv = reinterpret_cast<const float4*>(b2)[i & 31];
  reinterpret_cast<float4*>(out)[i] = bv;
}

// ---- reduce: out = b2 + sum over 8 H-eighth fp16 partials ----
__global__ void k_reduce(const unsigned* __restrict__ part, const float* __restrict__ b2,
                         float* __restrict__ out){
  int tid = blockIdx.x*256 + threadIdx.x;            // 0..2097151
  int m16 = tid & 15;
  int q   = (tid >> 4) & 3;
  int rr  = (tid >> 6) & 7;
  int i   = (tid >> 9) & 3;
  int j   = (tid >> 11) & 7;
  int tt  = tid >> 14;
  float s0 = 0.f, s1 = 0.f;
  #pragma unroll
  for (int hq = 0; hq < 8; ++hq){
    unsigned v = __builtin_nontemporal_load(part + (size_t)hq*2097152 + tid);
    half2v h = __builtin_bit_cast(half2v, v);
    s0 += (float)h[0];
    s1 += (float)h[1];
  }
  int tok0 = tt*32 + q*4 + i;          // tf=0 tokens
  int r = rr*16 + m16;
  float bb = b2[r];
  out[(size_t)tok0*1024 + j*128 + r]        = s0 + bb;
  out[(size_t)(tok0+16)*1024 + j*128 + r]   = s1 + bb;   // tf=1 tokens
}

// ---- main fused kernel ----
// grid 1024 x 512 thr (8 waves). block = (32 tokens) x (H-eighth 512).
// Wave w: GEMM1 owns nt pair (w*2, w*2+1) in each 256-col half; GEMM2 owns
// R-slice rr = w (16 cols), K = 512, w2 frags fully hoisted in registers.
// Level loop OUTER (j = 7..0): GEMM1(halfA) -> gelu -> buf0 -> sync ->
// [GEMM1(halfB) + GEMM2(buf0, kf0..7)] -> gelu -> buf1 -> sync ->
// GEMM2(buf1, kf8..15) -> store partial level j (256 B/wave contiguous).
__global__ __launch_bounds__(512, 4) void k_treemlp(
    const _Float16* __restrict__ xt, const _Float16* __restrict__ w1t,
    const _Float16* __restrict__ w2t, const float* __restrict__ b1,
    unsigned* __restrict__ partial, float* __restrict__ out, int use_partial){
  int b    = blockIdx.x;
  int hq   = b & 7;                     // H-eighth == XCD slot
  int tt   = b >> 3;                    // token tile 0..127
  int w    = threadIdx.x >> 6;          // wave 0..7
  int lane = threadIdx.x & 63;
  int m16 = lane & 15, q = lane >> 4;

  __shared__ _Float16 Pbuf[2*32*PROW];  // two P^T half-tiles, 33 KB

  // hoist all W2 fragments for this wave's R-slice (rr = w), K = 512
  half8 w2f[16];
  #pragma unroll
  for (int kf = 0; kf < 16; ++kf)
    w2f[kf] = *reinterpret_cast<const half8*>(
        w2t + ((size_t)((hq*16 + kf)*8 + w))*512 + lane*8);

  // GEMM1 suffix accumulators, init with b1 (snapshots = pre-act directly)
  f32x4 acc1[2][2][2];                  // [half it][nt hf][tok tf]
  #pragma unroll
  for (int it = 0; it < 2; ++it)
    #pragma unroll
    for (int hf = 0; hf < 2; ++hf){
      float4 bv = *reinterpret_cast<const float4*>(
          b1 + (size_t)(hq*32 + it*16 + w*2 + hf)*16 + q*4);
      #pragma unroll
      for (int tf = 0; tf < 2; ++tf)
        acc1[it][hf][tf] = f32x4{bv.x, bv.y, bv.z, bv.w};
    }

  const _Float16* xb0 = xt + (size_t)(tt*2 + 0)*16384 + lane*8;   // + kt*512
  const _Float16* xb1 = xt + (size_t)(tt*2 + 1)*16384 + lane*8;
  const _Float16* w1b = w1t + ((size_t)(hq*32 + w*2))*512 + lane*8; // + (kt*256 + it*16 + hf)*512

  unsigned* pbase = partial + (size_t)hq*2097152 + (size_t)tt*16384
                  + (size_t)w*64 + q*16 + m16;       // + (j*4 + i)*512
  float* obase = out + (size_t)(tt*32 + q*4)*1024 + w*16 + m16; // fallback path

  #pragma unroll
  for (int jr = 0; jr < 8; ++jr){
    int j = 7 - jr;                      // reverse K-block order -> suffix sums
    f32x4 outJ[2];
    outJ[0] = f32x4{0.f,0.f,0.f,0.f};
    outJ[1] = f32x4{0.f,0.f,0.f,0.f};

    // ---- phase A: GEMM1 for H-half 0 ----
    #pragma unroll
    for (int s = 0; s < 4; ++s){
      int kt = j*4 + s;
      half8 bx0 = *reinterpret_cast<const half8*>(xb0 + (size_t)kt*512);
      half8 bx1 = *reinterpret_cast<const half8*>(xb1 + (size_t)kt*512);
      half8 aw0 = *reinterpret_cast<const half8*>(w1b + (size_t)(kt*256    )*512);
      half8 aw1 = *reinterpret_cast<const half8*>(w1b + (size_t)(kt*256 + 1)*512);
      acc1[0][0][0] = MFMA16(aw0, bx0, acc1[0][0][0]);
      acc1[0][0][1] = MFMA16(aw0, bx1, acc1[0][0][1]);
      acc1[0][1][0] = MFMA16(aw1, bx0, acc1[0][1][0]);
      acc1[0][1][1] = MFMA16(aw1, bx1, acc1[0][1][1]);
    }
    // gelu snapshot -> buf0  ([tok][hcol] P^T tile, half4 b64 writes)
    #pragma unroll
    for (int hf = 0; hf < 2; ++hf)
      #pragma unroll
      for (int tf = 0; tf < 2; ++tf){
        half4 hv;
        #pragma unroll
        for (int i = 0; i < 4; ++i)
          hv[i] = (_Float16)gelu_f(acc1[0][hf][tf][i]);
        *reinterpret_cast<half4*>(Pbuf + (size_t)(tf*16 + m16)*PROW
                                  + w*32 + hf*16 + q*4) = hv;
      }
    __syncthreads();

    // ---- phase B: GEMM1 for H-half 1 (independent; loads issue early) ----
    #pragma unroll
    for (int s = 0; s < 4; ++s){
      int kt = j*4 + s;
      half8 bx0 = *reinterpret_cast<const half8*>(xb0 + (size_t)kt*512);
      half8 bx1 = *reinterpret_cast<const half8*>(xb1 + (size_t)kt*512);
      half8 aw0 = *reinterpret_cast<const half8*>(w1b + (size_t)(kt*256 + 16)*512);
      half8 aw1 = *reinterpret_cast<const half8*>(w1b + (size_t)(kt*256 + 17)*512);
      acc1[1][0][0] = MFMA16(aw0, bx0, acc1[1][0][0]);
      acc1[1][0][1] = MFMA16(aw0, bx1, acc1[1][0][1]);
      acc1[1][1][0] = MFMA16(aw1, bx0, acc1[1][1][0]);
      acc1[1][1][1] = MFMA16(aw1, bx1, acc1[1][1][1]);
    }
    // GEMM2 over buf0 (K-half 0, w2f[0..7])
    #pragma unroll
    for (int kf = 0; kf < 8; ++kf){
      half8 a0 = *reinterpret_cast<const half8*>(Pbuf + (size_t)m16*PROW + kf*32 + q*8);
      half8 a1 = *reinterpret_cast<const half8*>(Pbuf + (size_t)(16 + m16)*PROW + kf*32 + q*8);
      outJ[0] = MFMA16(a0, w2f[kf], outJ[0]);
      outJ[1] = MFMA16(a1, w2f[kf], outJ[1]);
    }
    // gelu snapshot -> buf1
    #pragma unroll
    for (int hf = 0; hf < 2; ++hf)
      #pragma unroll
      for (int tf = 0; tf < 2; ++tf){
        half4 hv;
        #pragma unroll
        for (int i = 0; i < 4; ++i)
          hv[i] = (_Float16)gelu_f(acc1[1][hf][tf][i]);
        *reinterpret_cast<half4*>(Pbuf + (size_t)(32 + tf*16 + m16)*PROW
                                  + w*32 + hf*16 + q*4) = hv;
      }
    __syncthreads();

    // ---- GEMM2 over buf1 (K-half 1, w2f[8..15]) ----
    #pragma unroll
    for (int kf = 0; kf < 8; ++kf){
      half8 a0 = *reinterpret_cast<const half8*>(Pbuf + (size_t)(32 + m16)*PROW + kf*32 + q*8);
      half8 a1 = *reinterpret_cast<const half8*>(Pbuf + (size_t)(48 + m16)*PROW + kf*32 + q*8);
      outJ[0] = MFMA16(a0, w2f[8 + kf], outJ[0]);
      outJ[1] = MFMA16(a1, w2f[8 + kf], outJ[1]);
    }

    // store partial for level j: 4x contiguous-256B nontemporal wave stores
    if (use_partial){
      #pragma unroll
      for (int i = 0; i < 4; ++i){
        half2v p;
        p[0] = (_Float16)outJ[0][i];
        p[1] = (_Float16)outJ[1][i];
        __builtin_nontemporal_store(__builtin_bit_cast(unsigned, p),
                                    pbase + (size_t)(j*4 + i)*512);
      }
    } else {
      #pragma unroll
      for (int i = 0; i < 4; ++i){
        atomicAdd(&obase[(size_t)i*1024 + j*128],          outJ[0][i]);
        atomicAdd(&obase[(size_t)(i+16)*1024 + j*128],     outJ[1][i]);
      }
    }
  }
}

extern "C" void kernel_launch(void* const* d_in, const int* in_sizes, int n_in,
                              void* d_out, int out_size, void* d_ws, size_t ws_size,
                              hipStream_t stream){
  (void)in_sizes; (void)n_in; (void)out_size;
  const float* x  = (const float*)d_in[0];
  const float* W1 = (const float*)d_in[1];
  const float* b1 = (const float*)d_in[2];
  const float* W2 = (const float*)d_in[3];
  const float* b2 = (const float*)d_in[4];
  float* out = (float*)d_out;

  _Float16* xt  = (_Float16*)d_ws;
  _Float16* w1t = xt  + 4194304;
  _Float16* w2t = w1t + 4194304;
  unsigned* partial = (unsigned*)(w2t + 524288);   // 64 MB packed fp16
  const size_t need = (size_t)(4194304 + 4194304 + 524288)*2 + (size_t)16777216*4;
  int use_partial = (ws_size >= need) ? 1 : 0;

  hipLaunchKernelGGL(k_prep, dim3(4352), dim3(256), 0, stream, x, W1, W2, xt, w1t, w2t);
  if (!use_partial)
    hipLaunchKernelGGL(k_init_out, dim3(4096), dim3(256), 0, stream, b2, out);
  hipLaunchKernelGGL(k_treemlp, dim3(1024), dim3(512), 0, stream,
                     xt, w1t, w2t, b1, partial, out, use_partial);
  if (use_partial)
    hipLaunchKernelGGL(k_reduce, dim3(8192), dim3(256), 0, stream, partial, b2, out);
}

// Round 6
// 210.238 us; speedup vs baseline: 2.1661x; 1.1624x over previous
//
#include <hip/hip_runtime.h>
#include <hip/hip_bf16.h>

// TreeMLP fused kernel for MI355X (gfx950), round 6.
//
// pre_l = b1 + sum_{j>=l} x_blockj @ W1_blockj  -> reverse-order K-loop with
// snapshots; GEMM2 fused per snapshot. R6 changes vs R5:
//  - T=64 tokens/block, GEMM1 via 32x32x16 MFMA (4 C-tiles/wave): W1 stream
//    halves (512 MB), 2x MFMA per loaded byte, grid 512 @ 1 block/CU
//  - x tile staged in LDS per level (16 KB dbuf, frag order, conflict-free)
//  - P stored in exact 16x16 A-frag order: GEMM2 reads lane-linear b128
//    (R5's [tok][hcol+pad] rows put 64 lanes on 8 banks: 10.5M conflict cyc)
//  - GEMM2 stays 16x16x32 so the full-K w2 hoist is 64 VGPRs
//
// ws layout:
//   xt : fp16 [128 tg][64 kf][64 lane][8]      8 MB   (32x32 B-frag order)
//   w1t: fp16 [8 hq][64 kf][16 ht][64 lane][8] 8 MB   (32x32 A-frag order)
//   w2t: fp16 [128 kt2][8 rt][64 lane][8]      1 MB   (16x16 B-frag order)
//   partial: u32 [8 hq][64 tt][8 j][4 i][2 tp][4 q][8 rw][16 m16]  64 MB
// total 84,934,656 B.

typedef _Float16 half8 __attribute__((ext_vector_type(8)));
typedef _Float16 half4 __attribute__((ext_vector_type(4)));
typedef _Float16 half2v __attribute__((ext_vector_type(2)));
typedef float    f32x4  __attribute__((ext_vector_type(4)));
typedef float    f32x16 __attribute__((ext_vector_type(16)));

#define MFMA3216(A,B,C) __builtin_amdgcn_mfma_f32_32x32x16_f16(A, B, C, 0, 0, 0)
#define MFMA1632(A,B,C) __builtin_amdgcn_mfma_f32_16x16x32_f16(A, B, C, 0, 0, 0)

__device__ __forceinline__ float gelu_f(float x){
  // 0.5x(1+tanh(c(x+0.044715x^3))) == x * sigmoid(x*(2c + 2c*0.044715*x^2))
  // folded with log2(e) for direct exp2
  float t2 = x * fmaf(x*x, -0.10294324f, -2.30220842f);
  float e  = __builtin_amdgcn_exp2f(t2);
  return x * __builtin_amdgcn_rcpf(1.0f + e);
}

// ---- fused prep: cast fp32->fp16 into MFMA fragment lane order ----
__global__ void k_prep(const float* __restrict__ x, const float* __restrict__ w1,
                       const float* __restrict__ w2,
                       _Float16* __restrict__ xt, _Float16* __restrict__ w1t,
                       _Float16* __restrict__ w2t){
  int bid = blockIdx.x;
  if (bid < 2048){                                   // xt: 32x32 B-frags
    int tid = bid*256 + threadIdx.x;                 // 524288 frag-lanes
    int lane = tid & 63;
    int kf   = (tid >> 6) & 63;
    int tgg  = tid >> 12;                            // token group of 32
    int tok = tgg*32 + (lane & 31);
    int k   = kf*16 + (lane >> 5)*8;
    const float4* s4 = reinterpret_cast<const float4*>(x + (size_t)tok*1024 + k);
    float4 a = s4[0], b = s4[1];
    half8 v;
    v[0]=(_Float16)a.x; v[1]=(_Float16)a.y; v[2]=(_Float16)a.z; v[3]=(_Float16)a.w;
    v[4]=(_Float16)b.x; v[5]=(_Float16)b.y; v[6]=(_Float16)b.z; v[7]=(_Float16)b.w;
    *reinterpret_cast<half8*>(xt + (size_t)tid*8) = v;
  } else if (bid < 4096){                            // w1t: 32x32 A-frags
    int tid = (bid - 2048)*256 + threadIdx.x;
    int lane = tid & 63;
    int ht   = (tid >> 6) & 15;
    int kf   = (tid >> 10) & 63;
    int hq   = tid >> 16;
    int n = hq*512 + ht*32 + (lane & 31);
    int k = kf*16 + (lane >> 5)*8;
    half8 v;
    #pragma unroll
    for (int jj = 0; jj < 8; ++jj) v[jj] = (_Float16)w1[(size_t)(k + jj)*4096 + n];
    *reinterpret_cast<half8*>(w1t + (size_t)tid*8) = v;
  } else {                                           // w2t: 16x16 B-frags
    int tid = (bid - 4096)*256 + threadIdx.x;
    int lane = tid & 63;
    int tile = tid >> 6;
    int ntr = tile & 7, kt2 = tile >> 3;
    int n = ntr*16 + (lane & 15);
    int k = kt2*32 + (lane >> 4)*8;
    half8 v;
    #pragma unroll
    for (int jj = 0; jj < 8; ++jj) v[jj] = (_Float16)w2[(size_t)(k + jj)*128 + n];
    *reinterpret_cast<half8*>(w2t + (size_t)tid*8) = v;
  }
}

__global__ void k_init_out(const float* __restrict__ b2, float* __restrict__ out){
  int i = blockIdx.x*256 + threadIdx.x;              // 1048576 float4s
  float4 bv = reinterpret_cast<const float4*>(b2)[i & 31];
  reinterpret_cast<float4*>(out)[i] = bv;
}

// ---- reduce: out = b2 + sum over 8 H-eighth fp16 partials ----
__global__ void k_reduce(const unsigned* __restrict__ part, const float* __restrict__ b2,
                         float* __restrict__ out){
  int tid = blockIdx.x*256 + threadIdx.x;            // 0..2097151
  int m16 = tid & 15;
  int rw  = (tid >> 4) & 7;
  int q   = (tid >> 7) & 3;
  int tp  = (tid >> 9) & 1;
  int i   = (tid >> 10) & 3;
  int j   = (tid >> 12) & 7;
  int tt  = tid >> 15;
  float s0 = 0.f, s1 = 0.f;
  #pragma unroll
  for (int hq = 0; hq < 8; ++hq){
    unsigned v = __builtin_nontemporal_load(part + (size_t)hq*2097152 + tid);
    half2v h = __builtin_bit_cast(half2v, v);
    s0 += (float)h[0];
    s1 += (float)h[1];
  }
  int r = rw*16 + m16;
  int tok0 = tt*64 + tp*32 + q*4 + i;                // tf = 2*tp
  float bb = b2[r];
  out[(size_t)tok0*1024 + j*128 + r]        = s0 + bb;
  out[(size_t)(tok0 + 16)*1024 + j*128 + r] = s1 + bb;   // tf = 2*tp+1
}

// ---- main fused kernel ----
// grid 512 x 512 thr (8 waves, 1 block/CU). block = (64 tok) x (H-eighth 512).
// GEMM1 (32x32x16, transposed): wave w owns hcol-tiles (w*2, w*2+1) for both
// 32-token groups -> acc1[2][2] f32x16, K reversed j=7..0 (suffix sums).
// gelu -> P in 16x16 A-frag order -> barrier -> GEMM2 (16x16x32): wave =
// R-slice w, 4 token-tiles, K=512 from hoisted w2f[16]; x_{j-1} staged to LDS
// in the same interval; partial level-j store; barrier.
__global__ __launch_bounds__(512, 2) void k_treemlp(
    const _Float16* __restrict__ xt, const _Float16* __restrict__ w1t,
    const _Float16* __restrict__ w2t, const float* __restrict__ b1,
    unsigned* __restrict__ partial, float* __restrict__ out, int use_partial){
  int b    = blockIdx.x;
  int hq   = b & 7;                     // H-eighth == XCD slot
  int tt   = b >> 3;                    // token tile 0..63 (64 tokens)
  int t    = threadIdx.x;
  int w    = t >> 6;                    // wave 0..7
  int lane = t & 63;
  int t32 = lane & 31, q2 = lane >> 5;
  int m16 = lane & 15, q4 = lane >> 4;

  __shared__ _Float16 Pbuf[32768];      // 64 KB: [tf 4][kf 16][lane 64][8]
  __shared__ _Float16 Xls[2][8192];     // 2 x 16 KB: [tg 2][ks 8][lane 64][8]

  // hoist all W2 fragments for this wave's R-slice (rw = w), K = 512
  half8 w2f[16];
  #pragma unroll
  for (int kf = 0; kf < 16; ++kf)
    w2f[kf] = *reinterpret_cast<const half8*>(
        w2t + (size_t)((hq*16 + kf)*8 + w)*512 + lane*8);

  // GEMM1 suffix accumulators (C^T: rows=hcol, cols=tok), init with b1
  f32x16 acc1[2][2];                    // [hcol-tile hf][tok-group tg]
  #pragma unroll
  for (int hf = 0; hf < 2; ++hf){
    int base = hq*512 + (w*2 + hf)*32;
    #pragma unroll
    for (int g = 0; g < 4; ++g){
      float4 bv = *reinterpret_cast<const float4*>(b1 + base + 8*g + 4*q2);
      #pragma unroll
      for (int c = 0; c < 4; ++c){
        acc1[hf][0][g*4 + c] = ((const float*)&bv)[c];
        acc1[hf][1][g*4 + c] = ((const float*)&bv)[c];
      }
    }
  }

  // ---- x staging: level j -> Xls[buf] (16 KB, frag order, 2 b128/thread)
  #define STAGE_X(J, BUF) do {                                              \
    int s0 = t, s1 = t + 512;                                               \
    half8 v0 = *reinterpret_cast<const half8*>(                             \
        xt + (size_t)((tt*2 + (s0 >> 9))*64 + (J)*8 + ((s0 >> 6) & 7))*512  \
           + (s0 & 63)*8);                                                  \
    half8 v1 = *reinterpret_cast<const half8*>(                             \
        xt + (size_t)((tt*2 + (s1 >> 9))*64 + (J)*8 + ((s1 >> 6) & 7))*512  \
           + (s1 & 63)*8);                                                  \
    *reinterpret_cast<half8*>(&Xls[BUF][s0*8]) = v0;                        \
    *reinterpret_cast<half8*>(&Xls[BUF][s1*8]) = v1;                        \
  } while (0)

  STAGE_X(7, 1);
  __syncthreads();

  const _Float16* w1base = w1t + (size_t)hq*65536*8 + (size_t)(w*2)*512 + lane*8;

  #pragma unroll
  for (int jr = 0; jr < 8; ++jr){
    int j = 7 - jr;                      // reverse K-block order -> suffix sums
    const _Float16* xb = Xls[j & 1];

    // ---- I1: GEMM1 level j (8 k-steps of 16) ----
    #pragma unroll
    for (int s = 0; s < 8; ++s){
      int kf = j*8 + s;
      half8 a0 = *reinterpret_cast<const half8*>(w1base + (size_t)(kf*16    )*512);
      half8 a1 = *reinterpret_cast<const half8*>(w1base + (size_t)(kf*16 + 1)*512);
      half8 x0 = *reinterpret_cast<const half8*>(xb + ((     s)*64 + lane)*8);
      half8 x1 = *reinterpret_cast<const half8*>(xb + ((8  + s)*64 + lane)*8);
      acc1[0][0] = MFMA3216(a0, x0, acc1[0][0]);
      acc1[0][1] = MFMA3216(a0, x1, acc1[0][1]);
      acc1[1][0] = MFMA3216(a1, x0, acc1[1][0]);
      acc1[1][1] = MFMA3216(a1, x1, acc1[1][1]);
    }

    // gelu snapshot -> P (16x16 A-frag order; writes are half4 b64)
    #pragma unroll
    for (int hf = 0; hf < 2; ++hf){
      int kfp = w*2 + hf;
      #pragma unroll
      for (int tg = 0; tg < 2; ++tg){
        int tf = tg*2 + (t32 >> 4);
        #pragma unroll
        for (int g = 0; g < 4; ++g){
          half4 hv;
          #pragma unroll
          for (int c = 0; c < 4; ++c)
            hv[c] = (_Float16)gelu_f(acc1[hf][tg][g*4 + c]);
          *reinterpret_cast<half4*>(
              Pbuf + ((tf*16 + kfp)*64 + g*16 + (t32 & 15))*8 + 4*q2) = hv;
        }
      }
    }
    __syncthreads();

    // ---- I2: GEMM2 level j (K=512) + stage x_{j-1} + partial store ----
    if (jr < 7) STAGE_X(j - 1, (j - 1) & 1);

    f32x4 outJ[4];
    #pragma unroll
    for (int tf = 0; tf < 4; ++tf) outJ[tf] = f32x4{0.f, 0.f, 0.f, 0.f};

    #pragma unroll
    for (int kf = 0; kf < 16; ++kf){
      #pragma unroll
      for (int tf = 0; tf < 4; ++tf){
        half8 a2 = *reinterpret_cast<const half8*>(
            Pbuf + ((tf*16 + kf)*64 + lane)*8);
        outJ[tf] = MFMA1632(a2, w2f[kf], outJ[tf]);
      }
    }

    if (use_partial){
      // u32 [hq][tt][j][i][tp][q][rw][m16]; per-instr: 4x 64B segments
      unsigned* pb = partial + (size_t)hq*2097152 + (size_t)tt*32768
                   + (size_t)j*4096 + q4*128 + w*16 + m16;
      #pragma unroll
      for (int i = 0; i < 4; ++i)
        #pragma unroll
        for (int tp = 0; tp < 2; ++tp){
          half2v p;
          p[0] = (_Float16)outJ[tp*2    ][i];
          p[1] = (_Float16)outJ[tp*2 + 1][i];
          __builtin_nontemporal_store(__builtin_bit_cast(unsigned, p),
                                      pb + (size_t)i*1024 + tp*512);
        }
    } else {
      #pragma unroll
      for (int tf = 0; tf < 4; ++tf)
        #pragma unroll
        for (int i = 0; i < 4; ++i){
          int tok = tt*64 + tf*16 + q4*4 + i;
          atomicAdd(out + (size_t)tok*1024 + j*128 + w*16 + m16, outJ[tf][i]);
        }
    }
    __syncthreads();
  }
  #undef STAGE_X
}

extern "C" void kernel_launch(void* const* d_in, const int* in_sizes, int n_in,
                              void* d_out, int out_size, void* d_ws, size_t ws_size,
                              hipStream_t stream){
  (void)in_sizes; (void)n_in; (void)out_size;
  const float* x  = (const float*)d_in[0];
  const float* W1 = (const float*)d_in[1];
  const float* b1 = (const float*)d_in[2];
  const float* W2 = (const float*)d_in[3];
  const float* b2 = (const float*)d_in[4];
  float* out = (float*)d_out;

  _Float16* xt  = (_Float16*)d_ws;
  _Float16* w1t = xt  + 4194304;
  _Float16* w2t = w1t + 4194304;
  unsigned* partial = (unsigned*)(w2t + 524288);   // 64 MB packed fp16
  const size_t need = (size_t)(4194304 + 4194304 + 524288)*2 + (size_t)16777216*4;
  int use_partial = (ws_size >= need) ? 1 : 0;

  hipLaunchKernelGGL(k_prep, dim3(4352), dim3(256), 0, stream, x, W1, W2, xt, w1t, w2t);
  if (!use_partial)
    hipLaunchKernelGGL(k_init_out, dim3(4096), dim3(256), 0, stream, b2, out);
  hipLaunchKernelGGL(k_treemlp, dim3(512), dim3(512), 0, stream,
                     xt, w1t, w2t, b1, partial, out, use_partial);
  if (use_partial)
    hipLaunchKernelGGL(k_reduce, dim3(8192), dim3(256), 0, stream, partial, b2, out);
}